// Round 9
// baseline (304.699 us; speedup 1.0000x reference)
//
#include <hip/hip_runtime.h>

// ---------------------------------------------------------------------------
// UnidirectionalAttn: B=4, S=2048, HIDDEN=1024, NH=16, HEAD=64
// prep(bf16, +pos) -> W transpose (single launch) -> QKV GEMM
// (BK=32 double-buffered global_load_lds, conflict-free (row>>1)&3 XOR
// swizzle, 32KB LDS) -> flash attn split-KV -> merge -> out GEMM (same dbuf).
// ---------------------------------------------------------------------------

typedef float f32x4 __attribute__((ext_vector_type(4)));
typedef short bf16x8 __attribute__((ext_vector_type(8)));   // 8 bf16 = 4 VGPRs
typedef short bf16x4 __attribute__((ext_vector_type(4)));   // 4 bf16 = 2 VGPRs

#define MFMA_BF16(a, b, c) __builtin_amdgcn_mfma_f32_16x16x32_bf16((a), (b), (c), 0, 0, 0)

#if __has_builtin(__builtin_amdgcn_mfma_f32_16x16x16bf16_1k)
#define HAVE_MFMA16 1
#define MFMA_BF16_K16(a, b, c) __builtin_amdgcn_mfma_f32_16x16x16bf16_1k((a), (b), (c), 0, 0, 0)
#else
#define HAVE_MFMA16 0
#endif

__device__ __forceinline__ short f2bf(float f) {
  union { float f; unsigned u; } v; v.f = f;
  unsigned u = v.u;
  u += 0x7fffu + ((u >> 16) & 1u);   // round-to-nearest-even
  return (short)(u >> 16);
}

__device__ __forceinline__ float bf2f(short s) {
  union { unsigned u; float f; } v;
  v.u = ((unsigned)(unsigned short)s) << 16;
  return v.f;
}

// direct v_exp_f32
__device__ __forceinline__ float fast_exp2(float x) {
#if __has_builtin(__builtin_amdgcn_exp2f)
  return __builtin_amdgcn_exp2f(x);
#else
  return exp2f(x);
#endif
}

// single-instruction packed f32x2 -> bf16x2 (RNE)
__device__ __forceinline__ int cvt_pk_bf16(float lo, float hi) {
  int r;
  asm("v_cvt_pk_bf16_f32 %0, %1, %2" : "=v"(r) : "v"(lo), "v"(hi));
  return r;
}

// async global->LDS 16B: per-lane global src, wave-uniform LDS base; HW
// writes base + lane*16 (guide m97/m104). size must be literal 16.
__device__ __forceinline__ void gl_lds16(const short* g, short* l) {
  __builtin_amdgcn_global_load_lds(
      (const __attribute__((address_space(1))) unsigned*)(g),
      (__attribute__((address_space(3))) unsigned*)(l), 16, 0, 0);
}

// LDS swizzles. Return SHORT index.
// [row][64-short] tiles (attn): XOR 16B-chunk with row&7.
__device__ __forceinline__ int swzK(int row, int colbyte) {
  return row * 64 + (((colbyte) ^ ((row & 7) << 4)) >> 1);
}
// [row][32-short (64B)] GEMM BK=32 tiles: XOR 16B-chunk with (row>>1)&3.
// Row stride = 16 banks -> start = 16*(row&1) + 4*(chunk^key). key=(row>>1)&3
// makes every consecutive-8-lane b128 group cover all 32 banks exactly once
// (row&3 key only covered 16 -> the 6.4M-conflict regression in r8).
__device__ __forceinline__ int swz32(int row, int colbyte) {
  return row * 32 + (((colbyte) ^ (((row >> 1) & 3) << 4)) >> 1);
}
// V: rotate 8B slots by row (injective in row&15) -> bf16x4 reads hit all banks
__device__ __forceinline__ int swzV(int row, int colbyte) {
  return row * 64 + ((((colbyte >> 3) + row) & 15) << 2);
}
// Epilogue scratch [128 rows][128 shorts], no pad: 16B-chunk XOR (16 chunks,
// 16-row period, bijective per row). col in shorts.
__device__ __forceinline__ int swzE(int row, int col) {
  return row * 128 + ((((col >> 3) ^ (row & 15)) << 3) | (col & 7));
}

// split-KV chunk tables: chunk = 12 KV tiles (768 kv). Per qt: nch=ceil((2qt+2)/12).
__device__ const int QT_X[30] = {5,6,7,8,9,10,11,11,12,12,13,13,14,14,15,15,
                                 4,10, 3,9,15, 2,8,14, 1,7,13, 0,6,12};
__device__ const int CH_X[30] = {0,0,0,0,0,0,0,1,0,1,0,1,0,1,0,1,
                                 0,1, 0,1,2, 0,1,2, 0,1,2, 0,1,2};
__device__ const int START_QT[16] = {0,1,2,3,4,5,6,8,10,12,14,16,18,21,24,27};

// ---------------------------------------------------------------------------
// Kernel 1: xb = bf16(x), xpb = bf16(x + pos)
// ---------------------------------------------------------------------------
__global__ __launch_bounds__(256) void prep_x(const float* __restrict__ x,
                                              const float* __restrict__ pos,
                                              short* __restrict__ xb,
                                              short* __restrict__ xpb) {
  int i = blockIdx.x * 256 + threadIdx.x;
  int idx = i * 4;
  const float4 xv = *(const float4*)(x + idx);
  const float4 pv = *(const float4*)(pos + (idx & ((2048 * 1024) - 1)));
  short4 a, b;
  a.x = f2bf(xv.x); a.y = f2bf(xv.y); a.z = f2bf(xv.z); a.w = f2bf(xv.w);
  b.x = f2bf(xv.x + pv.x); b.y = f2bf(xv.y + pv.y);
  b.z = f2bf(xv.z + pv.z); b.w = f2bf(xv.w + pv.w);
  *(short4*)(xb + idx) = a;
  *(short4*)(xpb + idx) = b;
}

// ---------------------------------------------------------------------------
// Kernel 2: both W transposes in ONE launch. [K=1024][N] f32 -> [N][K] bf16.
// blocks 0..95 -> Wqkv (N=3072); 96..127 -> Wo (N=1024).
// ---------------------------------------------------------------------------
__global__ __launch_bounds__(256) void transpose_w2(const float* __restrict__ wqkv,
                                                    const float* __restrict__ wo,
                                                    short* __restrict__ outqkv,
                                                    short* __restrict__ outo) {
  __shared__ float tile[32][33];
  const int bx = blockIdx.x;
  const float* __restrict__ in = (bx < 96) ? wqkv : wo;
  short* __restrict__ out = (bx < 96) ? outqkv : outo;
  const int N = (bx < 96) ? 3072 : 1024;
  const int n0 = ((bx < 96) ? bx : (bx - 96)) * 32;
  const int k0 = blockIdx.y * 32;
  int c = threadIdx.x & 31, r0 = threadIdx.x >> 5;
  for (int i = 0; i < 4; i++) {
    int r = r0 + i * 8;
    tile[r][c] = in[(size_t)(k0 + r) * N + n0 + c];
  }
  __syncthreads();
  for (int i = 0; i < 4; i++) {
    int r = r0 + i * 8;
    out[(size_t)(n0 + r) * 1024 + k0 + c] = f2bf(tile[c][r]);
  }
}

// ---------------------------------------------------------------------------
// Kernel 3: QKV GEMM (128x128 tile, BK=32 DOUBLE-BUFFERED). Per step:
// issue next tile's global_load_lds into the other buffer, then ds_read+MFMA
// the current one, then one barrier (its vmcnt(0) drain lands after compute).
// LDS 32KB: [buf0: A 4K|B 4K][buf1: A 4K|B 4K] shorts.
// ---------------------------------------------------------------------------
__global__ __launch_bounds__(256) void gemm_qkv(const short* __restrict__ xb,
                                                const short* __restrict__ xpb,
                                                const short* __restrict__ wt,
                                                short* __restrict__ qg,
                                                short* __restrict__ kg,
                                                short* __restrict__ vtg) {
  __shared__ __align__(16) short Sh[16384];   // 32 KB
  const int n = blockIdx.x;                 // 0..1535
  const int idx = n >> 3;
  const int bm = (n & 7) * 8 + (idx & 7);   // 0..63
  const int bn = idx >> 3;                  // 0..23
  const short* __restrict__ A = (bn < 16) ? xpb : xb;
  const int tid = threadIdx.x;
  const int lane = tid & 63, wid = tid >> 6;
  const int wm = wid & 1, wn = wid >> 1;
  const int quad = lane >> 4, l16 = lane & 15;
  const f32x4 fzero = {0.f, 0.f, 0.f, 0.f};
  f32x4 acc[4][4];
  for (int mt = 0; mt < 4; mt++)
    for (int nt = 0; nt < 4; nt++) acc[mt][nt] = fzero;
  const int arow0 = bm * 128, brow0 = bn * 128;

  // staging geometry (BK=32): slot p=(wid*2+i)*64+lane; row=p>>2; chunk=p&3
  int prow[2], pcol[2], pbase[2];
#pragma unroll
  for (int i = 0; i < 2; i++) {
    int p = (wid * 2 + i) * 64 + lane;
    prow[i] = p >> 2;
    pcol[i] = ((p & 3) ^ ((p >> 3) & 3)) * 8;   // inverse-swizzled src col (shorts)
    pbase[i] = (wid * 2 + i) * 512;
  }

#define STAGE_QKV(BUF, K0)                                                    \
  {                                                                           \
    _Pragma("unroll")                                                         \
    for (int i = 0; i < 2; i++) {                                             \
      gl_lds16(A + (size_t)(arow0 + prow[i]) * 1024 + (K0) + pcol[i],         \
               Sh + (BUF)*8192 + pbase[i]);                                   \
      gl_lds16(wt + (size_t)(brow0 + prow[i]) * 1024 + (K0) + pcol[i],        \
               Sh + (BUF)*8192 + 4096 + pbase[i]);                            \
    }                                                                         \
  }

#define COMPUTE_QKV(BASE)                                                     \
  {                                                                           \
    const short* As_ = (BASE);                                                \
    const short* Bs_ = (BASE) + 4096;                                         \
    bf16x8 af[4], bfr[4];                                                     \
    _Pragma("unroll")                                                         \
    for (int mt = 0; mt < 4; mt++)                                            \
      af[mt] = *(const bf16x8*)(As_ + swz32(wm * 64 + mt * 16 + l16, quad * 16)); \
    _Pragma("unroll")                                                         \
    for (int nt = 0; nt < 4; nt++)                                            \
      bfr[nt] = *(const bf16x8*)(Bs_ + swz32(wn * 64 + nt * 16 + l16, quad * 16)); \
    _Pragma("unroll")                                                         \
    for (int mt = 0; mt < 4; mt++)                                            \
      _Pragma("unroll")                                                       \
      for (int nt = 0; nt < 4; nt++)                                          \
        acc[mt][nt] = MFMA_BF16(af[mt], bfr[nt], acc[mt][nt]);                \
  }

  STAGE_QKV(0, 0);
  __syncthreads();                      // buf0 ready
  for (int t = 0; t < 32; t += 2) {
    if (t + 1 < 32) STAGE_QKV(1, (t + 1) * 32);
    COMPUTE_QKV(Sh);
    __syncthreads();                    // drains buf1 loads; buf0 free
    if (t + 2 < 32) STAGE_QKV(0, (t + 2) * 32);
    COMPUTE_QKV(Sh + 8192);
    __syncthreads();                    // drains buf0 loads; buf1 free
  }

  // ------ epilogue: LDS-bounced coalesced stores via swzE scratch ------
  short* Sf = Sh;                           // 16384 shorts = [128][128] swzE
  const int kk = bn >> 3;                   // 0=q 1=k 2=v (uniform per block)
  const int bglob = (bm * 128) >> 11;       // batch (uniform)
  const int s0v = (bm * 128) & 2047;
  if (kk == 2) {
    // V^T target [bh][h][s]: stage LDS[col][s], int2-packed along s
#pragma unroll
    for (int mt = 0; mt < 4; mt++)
#pragma unroll
      for (int nt = 0; nt < 4; nt++) {
        int col = wn * 64 + nt * 16 + l16;
        int sb = wm * 64 + mt * 16 + quad * 4;   // sb&7 in {0,4}: int2 stays in chunk
        int2 pk;
        pk.x = cvt_pk_bf16(acc[mt][nt][0], acc[mt][nt][1]);
        pk.y = cvt_pk_bf16(acc[mt][nt][2], acc[mt][nt][3]);
        *(int2*)(Sf + swzE(col, sb)) = pk;
      }
    __syncthreads();
    const int col = tid >> 1, half = tid & 1;
    int head = (bn * 2 + (col >> 6)) & 15;
    int hh = col & 63;
    int4* dst = (int4*)(vtg + (size_t)((bglob * 16 + head) * 64 + hh) * 2048 + s0v + half * 64);
#pragma unroll
    for (int c = 0; c < 8; c++)
      dst[c] = *(const int4*)(Sf + swzE(col, half * 64 + c * 8));
  } else {
    // q/k target [bh][s][h]: stage LDS[s][col], scalar writes
    const float scale = (kk == 0) ? 0.18033688f : 1.0f;   // 1/8 * log2(e)
#pragma unroll
    for (int mt = 0; mt < 4; mt++)
#pragma unroll
      for (int nt = 0; nt < 4; nt++) {
        int col = wn * 64 + nt * 16 + l16;
#pragma unroll
        for (int r = 0; r < 4; r++) {
          int s_loc = wm * 64 + mt * 16 + quad * 4 + r;
          Sf[swzE(s_loc, col)] = f2bf(acc[mt][nt][r] * scale);
        }
      }
    __syncthreads();
    const int row = tid >> 1, half = tid & 1;
    int head = (bn * 2 + half) & 15;
    short* __restrict__ dstp = (kk == 0) ? qg : kg;
    int4* dst = (int4*)(dstp + (size_t)((bglob * 16 + head) * 2048 + s0v + row) * 64);
#pragma unroll
    for (int c = 0; c < 8; c++)
      dst[c] = *(const int4*)(Sf + swzE(row, half * 64 + c * 8));
  }
}

// ---------------------------------------------------------------------------
// Kernel 4a: flash attention partials. 1D grid (1920), XCD-remapped (8 bh per
// XCD). Single-buffered 16KB KV tile + T14 load split. no-max exp2 softmax ->
// partials are ADDITIVE: unnormalized O^T (bf16) + l (f32).
// ---------------------------------------------------------------------------
__global__ __launch_bounds__(256, 3) void attn_part(const short* __restrict__ qg,
                                                    const short* __restrict__ kg,
                                                    const short* __restrict__ vtg,
                                                    short* __restrict__ pO,
                                                    float* __restrict__ pL) {
  const int n = blockIdx.x;                 // 0..1919; n&7 = XCD (round-robin)
  const int i = n >> 3;                     // 0..239
  const int bh = (n & 7) * 8 + i / 30;      // 8 bh per XCD, heavy-first slots
  const int slot = i % 30;
  const int qt = QT_X[slot], ch = CH_X[slot];
  const int p = bh * 30 + START_QT[qt] + ch;
  const short* __restrict__ Q = qg + (size_t)bh * 2048 * 64;
  const short* __restrict__ K = kg + (size_t)bh * 2048 * 64;
  const short* __restrict__ VT = vtg + (size_t)bh * 64 * 2048;
  __shared__ __align__(16) short KV[2][64 * 64];   // Ks=KV[0], Vs=KV[1]; 16 KB
  short* Ks = &KV[0][0];
  short* Vs = &KV[1][0];
#if !HAVE_MFMA16
  __shared__ __align__(16) short Ps[4][16 * 72];
#endif
  const int tid = threadIdx.x, lane = tid & 63, w = tid >> 6;
  const int quad = lane >> 4, l16 = lane & 15;
  const f32x4 fzero = {0.f, 0.f, 0.f, 0.f};

  bf16x8 bq[2][2];
#pragma unroll
  for (int sub = 0; sub < 2; sub++) {
    int qrow = qt * 128 + w * 32 + sub * 16 + l16;
#pragma unroll
    for (int ks = 0; ks < 2; ks++)
      bq[sub][ks] = *(const bf16x8*)(Q + (size_t)qrow * 64 + ks * 32 + quad * 8);
  }
  f32x4 acco[2][4];
  f32x4 lrun[2];
#pragma unroll
  for (int sub = 0; sub < 2; sub++) {
    for (int nt = 0; nt < 4; nt++) acco[sub][nt] = fzero;
    lrun[sub] = fzero;
  }

  const int kt0 = ch * 12;
  const int kt1 = min(kt0 + 12, 2 * qt + 2);   // exclusive
  const int qmin_w = qt * 128 + w * 32;

  const int sr0 = tid >> 3, sr1 = sr0 + 32;
  const int scs = (tid & 7) * 8;       // short col (global)
  const int scb = (tid & 7) * 16;      // byte col (LDS)
  const int oK0 = swzK(sr0, scb), oK1 = swzK(sr1, scb);
  const int oV0a = swzV(sr0, scb), oV0b = swzV(sr0, scb + 8);
  const int oV1a = swzV(sr1, scb), oV1b = swzV(sr1, scb + 8);

  int4 kreg[2], vreg[2];
  {
    int kv0 = kt0 * 64;
    kreg[0] = *(const int4*)(K + (size_t)(kv0 + sr0) * 64 + scs);
    kreg[1] = *(const int4*)(K + (size_t)(kv0 + sr1) * 64 + scs);
    vreg[0] = *(const int4*)(VT + (size_t)sr0 * 2048 + kv0 + scs);
    vreg[1] = *(const int4*)(VT + (size_t)sr1 * 2048 + kv0 + scs);
  }

  for (int kt = kt0; kt < kt1; kt++) {
    if (kt > kt0) __syncthreads();     // previous tile's compute fully drained
    *(int4*)(&Ks[oK0]) = kreg[0];
    *(int4*)(&Ks[oK1]) = kreg[1];
    *(int2*)(&Vs[oV0a]) = make_int2(vreg[0].x, vreg[0].y);
    *(int2*)(&Vs[oV0b]) = make_int2(vreg[0].z, vreg[0].w);
    *(int2*)(&Vs[oV1a]) = make_int2(vreg[1].x, vreg[1].y);
    *(int2*)(&Vs[oV1b]) = make_int2(vreg[1].z, vreg[1].w);
    __syncthreads();                   // tile visible

    if (kt + 1 < kt1) {                // T14: issue next loads; compute hides
      int kv0 = (kt + 1) * 64;
      kreg[0] = *(const int4*)(K + (size_t)(kv0 + sr0) * 64 + scs);
      kreg[1] = *(const int4*)(K + (size_t)(kv0 + sr1) * 64 + scs);
      vreg[0] = *(const int4*)(VT + (size_t)sr0 * 2048 + kv0 + scs);
      vreg[1] = *(const int4*)(VT + (size_t)sr1 * 2048 + kv0 + scs);
    }

    if (kt * 64 <= qmin_w + 31) {
      f32x4 accs[2][4];
#pragma unroll
      for (int sub = 0; sub < 2; sub++)
        for (int nt = 0; nt < 4; nt++) accs[sub][nt] = fzero;
      __builtin_amdgcn_s_setprio(1);
#pragma unroll
      for (int ks = 0; ks < 2; ks++)
#pragma unroll
        for (int nt = 0; nt < 4; nt++) {
          bf16x8 ak = *(const bf16x8*)(&Ks[swzK(nt * 16 + l16, ks * 64 + quad * 16)]);
          accs[0][nt] = MFMA_BF16(ak, bq[0][ks], accs[0][nt]);
          accs[1][nt] = MFMA_BF16(ak, bq[1][ks], accs[1][nt]);
        }
      __builtin_amdgcn_s_setprio(0);

      if ((kt + 1) * 64 > qmin_w) {        // partial-mask tile
#pragma unroll
        for (int sub = 0; sub < 2; sub++) {
          int q = qmin_w + sub * 16 + l16;
#pragma unroll
          for (int nt = 0; nt < 4; nt++) {
            int kv = kt * 64 + nt * 16 + quad * 4;
#pragma unroll
            for (int r = 0; r < 4; r++)
              if (kv + r > q) accs[sub][nt][r] = -1e30f;
          }
        }
      }

      // no-max softmax (scores in log2 units)
#pragma unroll
      for (int sub = 0; sub < 2; sub++)
#pragma unroll
        for (int nt = 0; nt < 4; nt++) {
#pragma unroll
          for (int r = 0; r < 4; r++) accs[sub][nt][r] = fast_exp2(accs[sub][nt][r]);
          lrun[sub] += accs[sub][nt];
        }

#if HAVE_MFMA16
      __builtin_amdgcn_s_setprio(1);
#pragma unroll
      for (int kkk = 0; kkk < 4; kkk++) {
        union { int2 i2; bf16x4 v; } p0, p1;
        p0.i2.x = cvt_pk_bf16(accs[0][kkk][0], accs[0][kkk][1]);
        p0.i2.y = cvt_pk_bf16(accs[0][kkk][2], accs[0][kkk][3]);
        p1.i2.x = cvt_pk_bf16(accs[1][kkk][0], accs[1][kkk][1]);
        p1.i2.y = cvt_pk_bf16(accs[1][kkk][2], accs[1][kkk][3]);
#pragma unroll
        for (int nth = 0; nth < 4; nth++) {
          bf16x4 av = *(const bf16x4*)(&Vs[swzV(nth * 16 + l16, kkk * 32 + quad * 8)]);
          acco[0][nth] = MFMA_BF16_K16(av, p0.v, acco[0][nth]);
          acco[1][nth] = MFMA_BF16_K16(av, p1.v, acco[1][nth]);
        }
      }
      __builtin_amdgcn_s_setprio(0);
#else
      short* P = Ps[w];
#pragma unroll
      for (int sub = 0; sub < 2; sub++) {
#pragma unroll
        for (int nt = 0; nt < 4; nt++) {
          int2 pk;
          pk.x = cvt_pk_bf16(accs[sub][nt][0], accs[sub][nt][1]);
          pk.y = cvt_pk_bf16(accs[sub][nt][2], accs[sub][nt][3]);
          *(int2*)(P + l16 * 72 + nt * 16 + quad * 4) = pk;
        }
#pragma unroll
        for (int ks2 = 0; ks2 < 2; ks2++) {
          bf16x8 bp = *(const bf16x8*)(P + l16 * 72 + ks2 * 32 + quad * 8);
#pragma unroll
          for (int nth = 0; nth < 4; nth++) {
            int r = nth * 16 + l16;
            int4 t4;
            *(int2*)&t4.x = *(const int2*)(&Vs[swzV(r, ks2 * 64 + quad * 16)]);
            *(int2*)&t4.z = *(const int2*)(&Vs[swzV(r, ks2 * 64 + quad * 16 + 8)]);
            bf16x8 av = *(const bf16x8*)&t4;
            acco[sub][nth] = MFMA_BF16(av, bp, acco[sub][nth]);
          }
        }
      }
#endif
    }
  }

  // l reduce + pL
#pragma unroll
  for (int sub = 0; sub < 2; sub++) {
    float lh = (lrun[sub][0] + lrun[sub][1]) + (lrun[sub][2] + lrun[sub][3]);
    lh += __shfl_xor(lh, 16);
    lh += __shfl_xor(lh, 32);
    int qloc = w * 32 + sub * 16 + l16;
    if (quad == 0) pL[p * 128 + qloc] = lh;
  }

  // O epilogue: bounce through KV (dead, exactly 16 KB = 128x64 bf16)
  __syncthreads();
  short* Ob = &KV[0][0];
#pragma unroll
  for (int sub = 0; sub < 2; sub++) {
    int qloc = w * 32 + sub * 16 + l16;
#pragma unroll
    for (int nth = 0; nth < 4; nth++) {
      int2 pk;
      pk.x = cvt_pk_bf16(acco[sub][nth][0], acco[sub][nth][1]);
      pk.y = cvt_pk_bf16(acco[sub][nth][2], acco[sub][nth][3]);
      *(int2*)(Ob + swzK(qloc, nth * 32 + quad * 8)) = pk;
    }
  }
  __syncthreads();
  {
    const int row = tid >> 1;
    const int hb = (tid & 1) * 64;
    int4 v0 = *(const int4*)(Ob + swzK(row, hb));
    int4 v1 = *(const int4*)(Ob + swzK(row, hb + 16));
    int4 v2 = *(const int4*)(Ob + swzK(row, hb + 32));
    int4 v3 = *(const int4*)(Ob + swzK(row, hb + 48));
    int4* dst = (int4*)(pO + (size_t)p * 8192 + tid * 32);
    dst[0] = v0; dst[1] = v1; dst[2] = v2; dst[3] = v3;
  }
}

// ---------------------------------------------------------------------------
// Kernel 4b: merge partials -> comb (bf16). 1D grid (1024), XCD-remapped.
// ---------------------------------------------------------------------------
__global__ __launch_bounds__(256) void attn_merge(const short* __restrict__ pO,
                                                  const float* __restrict__ pL,
                                                  short* __restrict__ comb) {
  const int n = blockIdx.x;                 // 0..1023
  const int i = n >> 3;                     // 0..127
  const int bh = (n & 7) * 8 + (i >> 4);    // same bh->XCD map as attn_part
  const int qt = i & 15;
  const int head = bh & 15, b = bh >> 4;
  const int nch = (2 * qt + 13) / 12;      // ceil((2qt+2)/12), 1..3
  const int p0 = bh * 30 + START_QT[qt];
  const int t = threadIdx.x;
  const int qloc = t >> 1, hh = (t & 1) * 32;

  float l = 0.f;
  for (int c = 0; c < nch; c++) l += pL[(p0 + c) * 128 + qloc];
  const float inv = 1.f / l;

  float acc[32];
#pragma unroll
  for (int j = 0; j < 32; j++) acc[j] = 0.f;
  for (int c = 0; c < nch; c++) {
    const short* src = pO + (size_t)(p0 + c) * 8192 + (size_t)qloc * 64 + hh;
#pragma unroll
    for (int v = 0; v < 4; v++) {
      short4 d0 = *(const short4*)(src + v * 8);
      short4 d1 = *(const short4*)(src + v * 8 + 4);
      acc[v * 8 + 0] += bf2f(d0.x); acc[v * 8 + 1] += bf2f(d0.y);
      acc[v * 8 + 2] += bf2f(d0.z); acc[v * 8 + 3] += bf2f(d0.w);
      acc[v * 8 + 4] += bf2f(d1.x); acc[v * 8 + 5] += bf2f(d1.y);
      acc[v * 8 + 6] += bf2f(d1.z); acc[v * 8 + 7] += bf2f(d1.w);
    }
  }
  size_t base = (size_t)(b * 2048 + qt * 128 + qloc) * 1024 + head * 64 + hh;
#pragma unroll
  for (int v = 0; v < 8; v++) {
    short4 sv;
    sv.x = f2bf(acc[v * 4 + 0] * inv);
    sv.y = f2bf(acc[v * 4 + 1] * inv);
    sv.z = f2bf(acc[v * 4 + 2] * inv);
    sv.w = f2bf(acc[v * 4 + 3] * inv);
    *(short4*)(comb + base + v * 4) = sv;
  }
}

// ---------------------------------------------------------------------------
// Kernel 5: out = comb @ Wo (fp32 stores). Same BK=32 dbuf as gemm_qkv.
// ---------------------------------------------------------------------------
__global__ __launch_bounds__(256) void gemm_out(const short* __restrict__ A,
                                                const short* __restrict__ wt,
                                                float* __restrict__ out) {
  __shared__ __align__(16) short Sh[16384];
  const int n = blockIdx.x;                 // 0..511
  const int idx = n >> 3;
  const int bm = (n & 7) * 8 + (idx & 7);   // 0..63
  const int bn = idx >> 3;                  // 0..7
  const int tid = threadIdx.x;
  const int lane = tid & 63, wid = tid >> 6;
  const int wm = wid & 1, wn = wid >> 1;
  const int quad = lane >> 4, l16 = lane & 15;
  const f32x4 fzero = {0.f, 0.f, 0.f, 0.f};
  f32x4 acc[4][4];
  for (int mt = 0; mt < 4; mt++)
    for (int nt = 0; nt < 4; nt++) acc[mt][nt] = fzero;
  const int arow0 = bm * 128, brow0 = bn * 128;

  int prow[2], pcol[2], pbase[2];
#pragma unroll
  for (int i = 0; i < 2; i++) {
    int p = (wid * 2 + i) * 64 + lane;
    prow[i] = p >> 2;
    pcol[i] = ((p & 3) ^ ((p >> 3) & 3)) * 8;
    pbase[i] = (wid * 2 + i) * 512;
  }

#define STAGE_OUT(BUF, K0)                                                    \
  {                                                                           \
    _Pragma("unroll")                                                         \
    for (int i = 0; i < 2; i++) {                                             \
      gl_lds16(A + (size_t)(arow0 + prow[i]) * 1024 + (K0) + pcol[i],         \
               Sh + (BUF)*8192 + pbase[i]);                                   \
      gl_lds16(wt + (size_t)(brow0 + prow[i]) * 1024 + (K0) + pcol[i],        \
               Sh + (BUF)*8192 + 4096 + pbase[i]);                            \
    }                                                                         \
  }

#define COMPUTE_OUT(BASE)                                                     \
  {                                                                           \
    const short* As_ = (BASE);                                                \
    const short* Bs_ = (BASE) + 4096;                                         \
    bf16x8 af[4], bfr[4];                                                     \
    _Pragma("unroll")                                                         \
    for (int mt = 0; mt < 4; mt++)                                            \
      af[mt] = *(const bf16x8*)(As_ + swz32(wm * 64 + mt * 16 + l16, quad * 16)); \
    _Pragma("unroll")                                                         \
    for (int nt = 0; nt < 4; nt++)                                            \
      bfr[nt] = *(const bf16x8*)(Bs_ + swz32(wn * 64 + nt * 16 + l16, quad * 16)); \
    _Pragma("unroll")                                                         \
    for (int mt = 0; mt < 4; mt++)                                            \
      _Pragma("unroll")                                                       \
      for (int nt = 0; nt < 4; nt++)                                          \
        acc[mt][nt] = MFMA_BF16(af[mt], bfr[nt], acc[mt][nt]);                \
  }

  STAGE_OUT(0, 0);
  __syncthreads();
  for (int t = 0; t < 32; t += 2) {
    if (t + 1 < 32) STAGE_OUT(1, (t + 1) * 32);
    COMPUTE_OUT(Sh);
    __syncthreads();
    if (t + 2 < 32) STAGE_OUT(0, (t + 2) * 32);
    COMPUTE_OUT(Sh + 8192);
    __syncthreads();
  }

  for (int nt = 0; nt < 4; nt++) {
    int col = bn * 128 + wn * 64 + nt * 16 + l16;
    for (int mt = 0; mt < 4; mt++) {
      int rowb = bm * 128 + wm * 64 + mt * 16 + quad * 4;
      for (int r = 0; r < 4; r++)
        out[(size_t)(rowb + r) * 1024 + col] = acc[mt][nt][r];
    }
  }
}

// ---------------------------------------------------------------------------
extern "C" void kernel_launch(void* const* d_in, const int* in_sizes, int n_in,
                              void* d_out, int out_size, void* d_ws, size_t ws_size,
                              hipStream_t stream) {
  const float* x    = (const float*)d_in[0];
  const float* pos  = (const float*)d_in[1];
  const float* Wqkv = (const float*)d_in[2];
  const float* Wo   = (const float*)d_in[3];
  float* out = (float*)d_out;

  char* ws = (char*)d_ws;
  const size_t SZ = (size_t)8192 * 1024 * 2;
  // [0, 2*SZ): xb/xpb during prep+gemm_qkv, then recycled as attn partials.
  short* xb    = (short*)(ws);
  short* xpb   = (short*)(ws + SZ);
  short* pO    = (short*)(ws);                          // 1920*8192*2 = 31.5 MB
  float* pL    = (float*)(ws + (size_t)1920 * 8192 * 2); // 1920*128*4 = 0.98 MB
  short* q     = (short*)(ws + 2 * SZ);
  short* k     = (short*)(ws + 3 * SZ);
  short* vt    = (short*)(ws + 4 * SZ);
  short* comb  = (short*)(ws + 5 * SZ);
  short* wqkvt = (short*)(ws + 6 * SZ);
  short* wot   = (short*)(ws + 6 * SZ + (size_t)3072 * 1024 * 2);

  prep_x<<<8192, 256, 0, stream>>>(x, pos, xb, xpb);
  transpose_w2<<<dim3(128, 32), 256, 0, stream>>>(Wqkv, Wo, wqkvt, wot);
  gemm_qkv<<<dim3(1536), 256, 0, stream>>>(xb, xpb, wqkvt, q, k, vt);
  attn_part<<<dim3(1920), 256, 0, stream>>>(q, k, vt, pO, pL);
  attn_merge<<<dim3(1024), 256, 0, stream>>>(pO, pL, comb);
  gemm_out<<<dim3(512), 256, 0, stream>>>(comb, wot, out);
}

// Round 10
// 275.576 us; speedup vs baseline: 1.1057x; 1.1057x over previous
//
#include <hip/hip_runtime.h>

// ---------------------------------------------------------------------------
// UnidirectionalAttn: B=4, S=2048, HIDDEN=1024, NH=16, HEAD=64
// fused prep(bf16,+pos)+W-transpose -> QKV GEMM (BK=32 double-buffered
// global_load_lds, r8 swizzle: conflicts 6.4M but HIDDEN at 2-phase (T2
// regime gate, m252) -- the "conflict-free" variant measured 19% SLOWER) ->
// flash attn split-KV -> merge -> out GEMM (same dbuf).
// ---------------------------------------------------------------------------

typedef float f32x4 __attribute__((ext_vector_type(4)));
typedef short bf16x8 __attribute__((ext_vector_type(8)));   // 8 bf16 = 4 VGPRs
typedef short bf16x4 __attribute__((ext_vector_type(4)));   // 4 bf16 = 2 VGPRs

#define MFMA_BF16(a, b, c) __builtin_amdgcn_mfma_f32_16x16x32_bf16((a), (b), (c), 0, 0, 0)

#if __has_builtin(__builtin_amdgcn_mfma_f32_16x16x16bf16_1k)
#define HAVE_MFMA16 1
#define MFMA_BF16_K16(a, b, c) __builtin_amdgcn_mfma_f32_16x16x16bf16_1k((a), (b), (c), 0, 0, 0)
#else
#define HAVE_MFMA16 0
#endif

__device__ __forceinline__ short f2bf(float f) {
  union { float f; unsigned u; } v; v.f = f;
  unsigned u = v.u;
  u += 0x7fffu + ((u >> 16) & 1u);   // round-to-nearest-even
  return (short)(u >> 16);
}

__device__ __forceinline__ float bf2f(short s) {
  union { unsigned u; float f; } v;
  v.u = ((unsigned)(unsigned short)s) << 16;
  return v.f;
}

// direct v_exp_f32
__device__ __forceinline__ float fast_exp2(float x) {
#if __has_builtin(__builtin_amdgcn_exp2f)
  return __builtin_amdgcn_exp2f(x);
#else
  return exp2f(x);
#endif
}

// single-instruction packed f32x2 -> bf16x2 (RNE)
__device__ __forceinline__ int cvt_pk_bf16(float lo, float hi) {
  int r;
  asm("v_cvt_pk_bf16_f32 %0, %1, %2" : "=v"(r) : "v"(lo), "v"(hi));
  return r;
}

// async global->LDS 16B: per-lane global src, wave-uniform LDS base; HW
// writes base + lane*16 (guide m97/m104). size must be literal 16.
__device__ __forceinline__ void gl_lds16(const short* g, short* l) {
  __builtin_amdgcn_global_load_lds(
      (const __attribute__((address_space(1))) unsigned*)(g),
      (__attribute__((address_space(3))) unsigned*)(l), 16, 0, 0);
}

// LDS swizzles. Return SHORT index.
// [row][64-short] tiles (attn): XOR 16B-chunk with row&7.
__device__ __forceinline__ int swzK(int row, int colbyte) {
  return row * 64 + (((colbyte) ^ ((row & 7) << 4)) >> 1);
}
// [row][32-short (64B)] GEMM BK=32 tiles: XOR 16B-chunk with row&3.
// NOTE: this has residual 6.4M bank-conflict cycles, but at the 2-phase
// schedule they are HIDDEN (T2 regime gate, m252) -- the conflict-free
// key ((row>>1)&3) measured 19% SLOWER via codegen side-effects (r9).
__device__ __forceinline__ int swz32(int row, int colbyte) {
  return row * 32 + (((colbyte) ^ ((row & 3) << 4)) >> 1);
}
// V: rotate 8B slots by row (injective in row&15) -> bf16x4 reads hit all banks
__device__ __forceinline__ int swzV(int row, int colbyte) {
  return row * 64 + ((((colbyte >> 3) + row) & 15) << 2);
}
// Epilogue scratch [128 rows][128 shorts], no pad: 16B-chunk XOR (16 chunks,
// 16-row period, bijective per row). col in shorts.
__device__ __forceinline__ int swzE(int row, int col) {
  return row * 128 + ((((col >> 3) ^ (row & 15)) << 3) | (col & 7));
}

// split-KV chunk tables: chunk = 12 KV tiles (768 kv). Per qt: nch=ceil((2qt+2)/12).
__device__ const int QT_X[30] = {5,6,7,8,9,10,11,11,12,12,13,13,14,14,15,15,
                                 4,10, 3,9,15, 2,8,14, 1,7,13, 0,6,12};
__device__ const int CH_X[30] = {0,0,0,0,0,0,0,1,0,1,0,1,0,1,0,1,
                                 0,1, 0,1,2, 0,1,2, 0,1,2, 0,1,2};
__device__ const int START_QT[16] = {0,1,2,3,4,5,6,8,10,12,14,16,18,21,24,27};

// ---------------------------------------------------------------------------
// Kernel 1 (fused): blocks 0..8191: xb = bf16(x), xpb = bf16(x + pos).
// blocks 8192..12287: W transposes ([K=1024][N] f32 -> [N][K] bf16;
// sub-blocks 0..95 -> Wqkv N=3072, 96..127 -> Wo N=1024; y-tiles folded in).
// Independent memory-bound work overlapped in one launch.
// ---------------------------------------------------------------------------
__global__ __launch_bounds__(256) void prep_and_transpose(
    const float* __restrict__ x, const float* __restrict__ pos,
    const float* __restrict__ wqkv, const float* __restrict__ wo,
    short* __restrict__ xb, short* __restrict__ xpb,
    short* __restrict__ outqkv, short* __restrict__ outo) {
  __shared__ float tile[32][33];
  const int n = blockIdx.x;
  if (n < 8192) {
    int i = n * 256 + threadIdx.x;
    int idx = i * 4;
    const float4 xv = *(const float4*)(x + idx);
    const float4 pv = *(const float4*)(pos + (idx & ((2048 * 1024) - 1)));
    short4 a, b;
    a.x = f2bf(xv.x); a.y = f2bf(xv.y); a.z = f2bf(xv.z); a.w = f2bf(xv.w);
    b.x = f2bf(xv.x + pv.x); b.y = f2bf(xv.y + pv.y);
    b.z = f2bf(xv.z + pv.z); b.w = f2bf(xv.w + pv.w);
    *(short4*)(xb + idx) = a;
    *(short4*)(xpb + idx) = b;
    return;
  }
  const int m = n - 8192;                   // 0..4095
  const int bx = m & 127;                   // 0..127
  const int k0 = (m >> 7) * 32;             // 0..992
  const float* __restrict__ in = (bx < 96) ? wqkv : wo;
  short* __restrict__ out = (bx < 96) ? outqkv : outo;
  const int N = (bx < 96) ? 3072 : 1024;
  const int n0 = ((bx < 96) ? bx : (bx - 96)) * 32;
  int c = threadIdx.x & 31, r0 = threadIdx.x >> 5;
  for (int i = 0; i < 4; i++) {
    int r = r0 + i * 8;
    tile[r][c] = in[(size_t)(k0 + r) * N + n0 + c];
  }
  __syncthreads();
  for (int i = 0; i < 4; i++) {
    int r = r0 + i * 8;
    out[(size_t)(n0 + r) * 1024 + k0 + c] = f2bf(tile[c][r]);
  }
}

// ---------------------------------------------------------------------------
// Kernel 3: QKV GEMM (128x128 tile, BK=32 DOUBLE-BUFFERED). Per step:
// issue next tile's global_load_lds into the other buffer, then ds_read+MFMA
// the current one, then one barrier (its vmcnt(0) drain lands after compute).
// LDS 32KB: [buf0: A 4K|B 4K][buf1: A 4K|B 4K] shorts.
// ---------------------------------------------------------------------------
__global__ __launch_bounds__(256) void gemm_qkv(const short* __restrict__ xb,
                                                const short* __restrict__ xpb,
                                                const short* __restrict__ wt,
                                                short* __restrict__ qg,
                                                short* __restrict__ kg,
                                                short* __restrict__ vtg) {
  __shared__ __align__(16) short Sh[16384];   // 32 KB
  const int n = blockIdx.x;                 // 0..1535
  const int idx = n >> 3;
  const int bm = (n & 7) * 8 + (idx & 7);   // 0..63
  const int bn = idx >> 3;                  // 0..23
  const short* __restrict__ A = (bn < 16) ? xpb : xb;
  const int tid = threadIdx.x;
  const int lane = tid & 63, wid = tid >> 6;
  const int wm = wid & 1, wn = wid >> 1;
  const int quad = lane >> 4, l16 = lane & 15;
  const f32x4 fzero = {0.f, 0.f, 0.f, 0.f};
  f32x4 acc[4][4];
  for (int mt = 0; mt < 4; mt++)
    for (int nt = 0; nt < 4; nt++) acc[mt][nt] = fzero;
  const int arow0 = bm * 128, brow0 = bn * 128;

  // staging geometry (BK=32): slot p=(wid*2+i)*64+lane; row=p>>2; chunk=p&3
  int prow[2], pcol[2], pbase[2];
#pragma unroll
  for (int i = 0; i < 2; i++) {
    int p = (wid * 2 + i) * 64 + lane;
    prow[i] = p >> 2;
    pcol[i] = ((p & 3) ^ ((p >> 2) & 3)) * 8;   // inverse-swizzled src col (shorts)
    pbase[i] = (wid * 2 + i) * 512;
  }

#define STAGE_QKV(BUF, K0)                                                    \
  {                                                                           \
    _Pragma("unroll")                                                         \
    for (int i = 0; i < 2; i++) {                                             \
      gl_lds16(A + (size_t)(arow0 + prow[i]) * 1024 + (K0) + pcol[i],         \
               Sh + (BUF)*8192 + pbase[i]);                                   \
      gl_lds16(wt + (size_t)(brow0 + prow[i]) * 1024 + (K0) + pcol[i],        \
               Sh + (BUF)*8192 + 4096 + pbase[i]);                            \
    }                                                                         \
  }

#define COMPUTE_QKV(BASE)                                                     \
  {                                                                           \
    const short* As_ = (BASE);                                                \
    const short* Bs_ = (BASE) + 4096;                                         \
    bf16x8 af[4], bfr[4];                                                     \
    _Pragma("unroll")                                                         \
    for (int mt = 0; mt < 4; mt++)                                            \
      af[mt] = *(const bf16x8*)(As_ + swz32(wm * 64 + mt * 16 + l16, quad * 16)); \
    _Pragma("unroll")                                                         \
    for (int nt = 0; nt < 4; nt++)                                            \
      bfr[nt] = *(const bf16x8*)(Bs_ + swz32(wn * 64 + nt * 16 + l16, quad * 16)); \
    _Pragma("unroll")                                                         \
    for (int mt = 0; mt < 4; mt++)                                            \
      _Pragma("unroll")                                                       \
      for (int nt = 0; nt < 4; nt++)                                          \
        acc[mt][nt] = MFMA_BF16(af[mt], bfr[nt], acc[mt][nt]);                \
  }

  STAGE_QKV(0, 0);
  __syncthreads();                      // buf0 ready
  for (int t = 0; t < 32; t += 2) {
    if (t + 1 < 32) STAGE_QKV(1, (t + 1) * 32);
    COMPUTE_QKV(Sh);
    __syncthreads();                    // drains buf1 loads; buf0 free
    if (t + 2 < 32) STAGE_QKV(0, (t + 2) * 32);
    COMPUTE_QKV(Sh + 8192);
    __syncthreads();                    // drains buf0 loads; buf1 free
  }

  // ------ epilogue: LDS-bounced coalesced stores via swzE scratch ------
  short* Sf = Sh;                           // 16384 shorts = [128][128] swzE
  const int kk = bn >> 3;                   // 0=q 1=k 2=v (uniform per block)
  const int bglob = (bm * 128) >> 11;       // batch (uniform)
  const int s0v = (bm * 128) & 2047;
  if (kk == 2) {
    // V^T target [bh][h][s]: stage LDS[col][s], int2-packed along s
#pragma unroll
    for (int mt = 0; mt < 4; mt++)
#pragma unroll
      for (int nt = 0; nt < 4; nt++) {
        int col = wn * 64 + nt * 16 + l16;
        int sb = wm * 64 + mt * 16 + quad * 4;   // sb&7 in {0,4}: int2 stays in chunk
        int2 pk;
        pk.x = cvt_pk_bf16(acc[mt][nt][0], acc[mt][nt][1]);
        pk.y = cvt_pk_bf16(acc[mt][nt][2], acc[mt][nt][3]);
        *(int2*)(Sf + swzE(col, sb)) = pk;
      }
    __syncthreads();
    const int col = tid >> 1, half = tid & 1;
    int head = (bn * 2 + (col >> 6)) & 15;
    int hh = col & 63;
    int4* dst = (int4*)(vtg + (size_t)((bglob * 16 + head) * 64 + hh) * 2048 + s0v + half * 64);
#pragma unroll
    for (int c = 0; c < 8; c++)
      dst[c] = *(const int4*)(Sf + swzE(col, half * 64 + c * 8));
  } else {
    // q/k target [bh][s][h]: stage LDS[s][col], scalar writes
    const float scale = (kk == 0) ? 0.18033688f : 1.0f;   // 1/8 * log2(e)
#pragma unroll
    for (int mt = 0; mt < 4; mt++)
#pragma unroll
      for (int nt = 0; nt < 4; nt++) {
        int col = wn * 64 + nt * 16 + l16;
#pragma unroll
        for (int r = 0; r < 4; r++) {
          int s_loc = wm * 64 + mt * 16 + quad * 4 + r;
          Sf[swzE(s_loc, col)] = f2bf(acc[mt][nt][r] * scale);
        }
      }
    __syncthreads();
    const int row = tid >> 1, half = tid & 1;
    int head = (bn * 2 + half) & 15;
    short* __restrict__ dstp = (kk == 0) ? qg : kg;
    int4* dst = (int4*)(dstp + (size_t)((bglob * 16 + head) * 2048 + s0v + row) * 64);
#pragma unroll
    for (int c = 0; c < 8; c++)
      dst[c] = *(const int4*)(Sf + swzE(row, half * 64 + c * 8));
  }
}

// ---------------------------------------------------------------------------
// Kernel 4a: flash attention partials. 1D grid (1920), XCD-remapped (8 bh per
// XCD). Single-buffered 16KB KV tile + T14 load split. no-max exp2 softmax ->
// partials are ADDITIVE: unnormalized O^T (bf16) + l (f32).
// ---------------------------------------------------------------------------
__global__ __launch_bounds__(256, 3) void attn_part(const short* __restrict__ qg,
                                                    const short* __restrict__ kg,
                                                    const short* __restrict__ vtg,
                                                    short* __restrict__ pO,
                                                    float* __restrict__ pL) {
  const int n = blockIdx.x;                 // 0..1919; n&7 = XCD (round-robin)
  const int i = n >> 3;                     // 0..239
  const int bh = (n & 7) * 8 + i / 30;      // 8 bh per XCD, heavy-first slots
  const int slot = i % 30;
  const int qt = QT_X[slot], ch = CH_X[slot];
  const int p = bh * 30 + START_QT[qt] + ch;
  const short* __restrict__ Q = qg + (size_t)bh * 2048 * 64;
  const short* __restrict__ K = kg + (size_t)bh * 2048 * 64;
  const short* __restrict__ VT = vtg + (size_t)bh * 64 * 2048;
  __shared__ __align__(16) short KV[2][64 * 64];   // Ks=KV[0], Vs=KV[1]; 16 KB
  short* Ks = &KV[0][0];
  short* Vs = &KV[1][0];
#if !HAVE_MFMA16
  __shared__ __align__(16) short Ps[4][16 * 72];
#endif
  const int tid = threadIdx.x, lane = tid & 63, w = tid >> 6;
  const int quad = lane >> 4, l16 = lane & 15;
  const f32x4 fzero = {0.f, 0.f, 0.f, 0.f};

  bf16x8 bq[2][2];
#pragma unroll
  for (int sub = 0; sub < 2; sub++) {
    int qrow = qt * 128 + w * 32 + sub * 16 + l16;
#pragma unroll
    for (int ks = 0; ks < 2; ks++)
      bq[sub][ks] = *(const bf16x8*)(Q + (size_t)qrow * 64 + ks * 32 + quad * 8);
  }
  f32x4 acco[2][4];
  f32x4 lrun[2];
#pragma unroll
  for (int sub = 0; sub < 2; sub++) {
    for (int nt = 0; nt < 4; nt++) acco[sub][nt] = fzero;
    lrun[sub] = fzero;
  }

  const int kt0 = ch * 12;
  const int kt1 = min(kt0 + 12, 2 * qt + 2);   // exclusive
  const int qmin_w = qt * 128 + w * 32;

  const int sr0 = tid >> 3, sr1 = sr0 + 32;
  const int scs = (tid & 7) * 8;       // short col (global)
  const int scb = (tid & 7) * 16;      // byte col (LDS)
  const int oK0 = swzK(sr0, scb), oK1 = swzK(sr1, scb);
  const int oV0a = swzV(sr0, scb), oV0b = swzV(sr0, scb + 8);
  const int oV1a = swzV(sr1, scb), oV1b = swzV(sr1, scb + 8);

  int4 kreg[2], vreg[2];
  {
    int kv0 = kt0 * 64;
    kreg[0] = *(const int4*)(K + (size_t)(kv0 + sr0) * 64 + scs);
    kreg[1] = *(const int4*)(K + (size_t)(kv0 + sr1) * 64 + scs);
    vreg[0] = *(const int4*)(VT + (size_t)sr0 * 2048 + kv0 + scs);
    vreg[1] = *(const int4*)(VT + (size_t)sr1 * 2048 + kv0 + scs);
  }

  for (int kt = kt0; kt < kt1; kt++) {
    if (kt > kt0) __syncthreads();     // previous tile's compute fully drained
    *(int4*)(&Ks[oK0]) = kreg[0];
    *(int4*)(&Ks[oK1]) = kreg[1];
    *(int2*)(&Vs[oV0a]) = make_int2(vreg[0].x, vreg[0].y);
    *(int2*)(&Vs[oV0b]) = make_int2(vreg[0].z, vreg[0].w);
    *(int2*)(&Vs[oV1a]) = make_int2(vreg[1].x, vreg[1].y);
    *(int2*)(&Vs[oV1b]) = make_int2(vreg[1].z, vreg[1].w);
    __syncthreads();                   // tile visible

    if (kt + 1 < kt1) {                // T14: issue next loads; compute hides
      int kv0 = (kt + 1) * 64;
      kreg[0] = *(const int4*)(K + (size_t)(kv0 + sr0) * 64 + scs);
      kreg[1] = *(const int4*)(K + (size_t)(kv0 + sr1) * 64 + scs);
      vreg[0] = *(const int4*)(VT + (size_t)sr0 * 2048 + kv0 + scs);
      vreg[1] = *(const int4*)(VT + (size_t)sr1 * 2048 + kv0 + scs);
    }

    if (kt * 64 <= qmin_w + 31) {
      f32x4 accs[2][4];
#pragma unroll
      for (int sub = 0; sub < 2; sub++)
        for (int nt = 0; nt < 4; nt++) accs[sub][nt] = fzero;
      __builtin_amdgcn_s_setprio(1);
#pragma unroll
      for (int ks = 0; ks < 2; ks++)
#pragma unroll
        for (int nt = 0; nt < 4; nt++) {
          bf16x8 ak = *(const bf16x8*)(&Ks[swzK(nt * 16 + l16, ks * 64 + quad * 16)]);
          accs[0][nt] = MFMA_BF16(ak, bq[0][ks], accs[0][nt]);
          accs[1][nt] = MFMA_BF16(ak, bq[1][ks], accs[1][nt]);
        }
      __builtin_amdgcn_s_setprio(0);

      if ((kt + 1) * 64 > qmin_w) {        // partial-mask tile
#pragma unroll
        for (int sub = 0; sub < 2; sub++) {
          int q = qmin_w + sub * 16 + l16;
#pragma unroll
          for (int nt = 0; nt < 4; nt++) {
            int kv = kt * 64 + nt * 16 + quad * 4;
#pragma unroll
            for (int r = 0; r < 4; r++)
              if (kv + r > q) accs[sub][nt][r] = -1e30f;
          }
        }
      }

      // no-max softmax (scores in log2 units)
#pragma unroll
      for (int sub = 0; sub < 2; sub++)
#pragma unroll
        for (int nt = 0; nt < 4; nt++) {
#pragma unroll
          for (int r = 0; r < 4; r++) accs[sub][nt][r] = fast_exp2(accs[sub][nt][r]);
          lrun[sub] += accs[sub][nt];
        }

#if HAVE_MFMA16
      __builtin_amdgcn_s_setprio(1);
#pragma unroll
      for (int kkk = 0; kkk < 4; kkk++) {
        union { int2 i2; bf16x4 v; } p0, p1;
        p0.i2.x = cvt_pk_bf16(accs[0][kkk][0], accs[0][kkk][1]);
        p0.i2.y = cvt_pk_bf16(accs[0][kkk][2], accs[0][kkk][3]);
        p1.i2.x = cvt_pk_bf16(accs[1][kkk][0], accs[1][kkk][1]);
        p1.i2.y = cvt_pk_bf16(accs[1][kkk][2], accs[1][kkk][3]);
#pragma unroll
        for (int nth = 0; nth < 4; nth++) {
          bf16x4 av = *(const bf16x4*)(&Vs[swzV(nth * 16 + l16, kkk * 32 + quad * 8)]);
          acco[0][nth] = MFMA_BF16_K16(av, p0.v, acco[0][nth]);
          acco[1][nth] = MFMA_BF16_K16(av, p1.v, acco[1][nth]);
        }
      }
      __builtin_amdgcn_s_setprio(0);
#else
      short* P = Ps[w];
#pragma unroll
      for (int sub = 0; sub < 2; sub++) {
#pragma unroll
        for (int nt = 0; nt < 4; nt++) {
          int2 pk;
          pk.x = cvt_pk_bf16(accs[sub][nt][0], accs[sub][nt][1]);
          pk.y = cvt_pk_bf16(accs[sub][nt][2], accs[sub][nt][3]);
          *(int2*)(P + l16 * 72 + nt * 16 + quad * 4) = pk;
        }
#pragma unroll
        for (int ks2 = 0; ks2 < 2; ks2++) {
          bf16x8 bp = *(const bf16x8*)(P + l16 * 72 + ks2 * 32 + quad * 8);
#pragma unroll
          for (int nth = 0; nth < 4; nth++) {
            int r = nth * 16 + l16;
            int4 t4;
            *(int2*)&t4.x = *(const int2*)(&Vs[swzV(r, ks2 * 64 + quad * 16)]);
            *(int2*)&t4.z = *(const int2*)(&Vs[swzV(r, ks2 * 64 + quad * 16 + 8)]);
            bf16x8 av = *(const bf16x8*)&t4;
            acco[sub][nth] = MFMA_BF16(av, bp, acco[sub][nth]);
          }
        }
      }
#endif
    }
  }

  // l reduce + pL
#pragma unroll
  for (int sub = 0; sub < 2; sub++) {
    float lh = (lrun[sub][0] + lrun[sub][1]) + (lrun[sub][2] + lrun[sub][3]);
    lh += __shfl_xor(lh, 16);
    lh += __shfl_xor(lh, 32);
    int qloc = w * 32 + sub * 16 + l16;
    if (quad == 0) pL[p * 128 + qloc] = lh;
  }

  // O epilogue: bounce through KV (dead, exactly 16 KB = 128x64 bf16)
  __syncthreads();
  short* Ob = &KV[0][0];
#pragma unroll
  for (int sub = 0; sub < 2; sub++) {
    int qloc = w * 32 + sub * 16 + l16;
#pragma unroll
    for (int nth = 0; nth < 4; nth++) {
      int2 pk;
      pk.x = cvt_pk_bf16(acco[sub][nth][0], acco[sub][nth][1]);
      pk.y = cvt_pk_bf16(acco[sub][nth][2], acco[sub][nth][3]);
      *(int2*)(Ob + swzK(qloc, nth * 32 + quad * 8)) = pk;
    }
  }
  __syncthreads();
  {
    const int row = tid >> 1;
    const int hb = (tid & 1) * 64;
    int4 v0 = *(const int4*)(Ob + swzK(row, hb));
    int4 v1 = *(const int4*)(Ob + swzK(row, hb + 16));
    int4 v2 = *(const int4*)(Ob + swzK(row, hb + 32));
    int4 v3 = *(const int4*)(Ob + swzK(row, hb + 48));
    int4* dst = (int4*)(pO + (size_t)p * 8192 + tid * 32);
    dst[0] = v0; dst[1] = v1; dst[2] = v2; dst[3] = v3;
  }
}

// ---------------------------------------------------------------------------
// Kernel 4b: merge partials -> comb (bf16). 1D grid (1024), XCD-remapped.
// ---------------------------------------------------------------------------
__global__ __launch_bounds__(256) void attn_merge(const short* __restrict__ pO,
                                                  const float* __restrict__ pL,
                                                  short* __restrict__ comb) {
  const int n = blockIdx.x;                 // 0..1023
  const int i = n >> 3;                     // 0..127
  const int bh = (n & 7) * 8 + (i >> 4);    // same bh->XCD map as attn_part
  const int qt = i & 15;
  const int head = bh & 15, b = bh >> 4;
  const int nch = (2 * qt + 13) / 12;      // ceil((2qt+2)/12), 1..3
  const int p0 = bh * 30 + START_QT[qt];
  const int t = threadIdx.x;
  const int qloc = t >> 1, hh = (t & 1) * 32;

  float l = 0.f;
  for (int c = 0; c < nch; c++) l += pL[(p0 + c) * 128 + qloc];
  const float inv = 1.f / l;

  float acc[32];
#pragma unroll
  for (int j = 0; j < 32; j++) acc[j] = 0.f;
  for (int c = 0; c < nch; c++) {
    const short* src = pO + (size_t)(p0 + c) * 8192 + (size_t)qloc * 64 + hh;
#pragma unroll
    for (int v = 0; v < 4; v++) {
      short4 d0 = *(const short4*)(src + v * 8);
      short4 d1 = *(const short4*)(src + v * 8 + 4);
      acc[v * 8 + 0] += bf2f(d0.x); acc[v * 8 + 1] += bf2f(d0.y);
      acc[v * 8 + 2] += bf2f(d0.z); acc[v * 8 + 3] += bf2f(d0.w);
      acc[v * 8 + 4] += bf2f(d1.x); acc[v * 8 + 5] += bf2f(d1.y);
      acc[v * 8 + 6] += bf2f(d1.z); acc[v * 8 + 7] += bf2f(d1.w);
    }
  }
  size_t base = (size_t)(b * 2048 + qt * 128 + qloc) * 1024 + head * 64 + hh;
#pragma unroll
  for (int v = 0; v < 8; v++) {
    short4 sv;
    sv.x = f2bf(acc[v * 4 + 0] * inv);
    sv.y = f2bf(acc[v * 4 + 1] * inv);
    sv.z = f2bf(acc[v * 4 + 2] * inv);
    sv.w = f2bf(acc[v * 4 + 3] * inv);
    *(short4*)(comb + base + v * 4) = sv;
  }
}

// ---------------------------------------------------------------------------
// Kernel 5: out = comb @ Wo (fp32 stores). Same BK=32 dbuf as gemm_qkv.
// ---------------------------------------------------------------------------
__global__ __launch_bounds__(256) void gemm_out(const short* __restrict__ A,
                                                const short* __restrict__ wt,
                                                float* __restrict__ out) {
  __shared__ __align__(16) short Sh[16384];
  const int n = blockIdx.x;                 // 0..511
  const int idx = n >> 3;
  const int bm = (n & 7) * 8 + (idx & 7);   // 0..63
  const int bn = idx >> 3;                  // 0..7
  const int tid = threadIdx.x;
  const int lane = tid & 63, wid = tid >> 6;
  const int wm = wid & 1, wn = wid >> 1;
  const int quad = lane >> 4, l16 = lane & 15;
  const f32x4 fzero = {0.f, 0.f, 0.f, 0.f};
  f32x4 acc[4][4];
  for (int mt = 0; mt < 4; mt++)
    for (int nt = 0; nt < 4; nt++) acc[mt][nt] = fzero;
  const int arow0 = bm * 128, brow0 = bn * 128;

  int prow[2], pcol[2], pbase[2];
#pragma unroll
  for (int i = 0; i < 2; i++) {
    int p = (wid * 2 + i) * 64 + lane;
    prow[i] = p >> 2;
    pcol[i] = ((p & 3) ^ ((p >> 2) & 3)) * 8;
    pbase[i] = (wid * 2 + i) * 512;
  }

#define STAGE_OUT(BUF, K0)                                                    \
  {                                                                           \
    _Pragma("unroll")                                                         \
    for (int i = 0; i < 2; i++) {                                             \
      gl_lds16(A + (size_t)(arow0 + prow[i]) * 1024 + (K0) + pcol[i],         \
               Sh + (BUF)*8192 + pbase[i]);                                   \
      gl_lds16(wt + (size_t)(brow0 + prow[i]) * 1024 + (K0) + pcol[i],        \
               Sh + (BUF)*8192 + 4096 + pbase[i]);                            \
    }                                                                         \
  }

#define COMPUTE_OUT(BASE)                                                     \
  {                                                                           \
    const short* As_ = (BASE);                                                \
    const short* Bs_ = (BASE) + 4096;                                         \
    bf16x8 af[4], bfr[4];                                                     \
    _Pragma("unroll")                                                         \
    for (int mt = 0; mt < 4; mt++)                                            \
      af[mt] = *(const bf16x8*)(As_ + swz32(wm * 64 + mt * 16 + l16, quad * 16)); \
    _Pragma("unroll")                                                         \
    for (int nt = 0; nt < 4; nt++)                                            \
      bfr[nt] = *(const bf16x8*)(Bs_ + swz32(wn * 64 + nt * 16 + l16, quad * 16)); \
    _Pragma("unroll")                                                         \
    for (int mt = 0; mt < 4; mt++)                                            \
      _Pragma("unroll")                                                       \
      for (int nt = 0; nt < 4; nt++)                                          \
        acc[mt][nt] = MFMA_BF16(af[mt], bfr[nt], acc[mt][nt]);                \
  }

  STAGE_OUT(0, 0);
  __syncthreads();
  for (int t = 0; t < 32; t += 2) {
    if (t + 1 < 32) STAGE_OUT(1, (t + 1) * 32);
    COMPUTE_OUT(Sh);
    __syncthreads();
    if (t + 2 < 32) STAGE_OUT(0, (t + 2) * 32);
    COMPUTE_OUT(Sh + 8192);
    __syncthreads();
  }

  for (int nt = 0; nt < 4; nt++) {
    int col = bn * 128 + wn * 64 + nt * 16 + l16;
    for (int mt = 0; mt < 4; mt++) {
      int rowb = bm * 128 + wm * 64 + mt * 16 + quad * 4;
      for (int r = 0; r < 4; r++)
        out[(size_t)(rowb + r) * 1024 + col] = acc[mt][nt][r];
    }
  }
}

// ---------------------------------------------------------------------------
extern "C" void kernel_launch(void* const* d_in, const int* in_sizes, int n_in,
                              void* d_out, int out_size, void* d_ws, size_t ws_size,
                              hipStream_t stream) {
  const float* x    = (const float*)d_in[0];
  const float* pos  = (const float*)d_in[1];
  const float* Wqkv = (const float*)d_in[2];
  const float* Wo   = (const float*)d_in[3];
  float* out = (float*)d_out;

  char* ws = (char*)d_ws;
  const size_t SZ = (size_t)8192 * 1024 * 2;
  // [0, 2*SZ): xb/xpb during prep+gemm_qkv, then recycled as attn partials.
  short* xb    = (short*)(ws);
  short* xpb   = (short*)(ws + SZ);
  short* pO    = (short*)(ws);                          // 1920*8192*2 = 31.5 MB
  float* pL    = (float*)(ws + (size_t)1920 * 8192 * 2); // 1920*128*4 = 0.98 MB
  short* q     = (short*)(ws + 2 * SZ);
  short* k     = (short*)(ws + 3 * SZ);
  short* vt    = (short*)(ws + 4 * SZ);
  short* comb  = (short*)(ws + 5 * SZ);
  short* wqkvt = (short*)(ws + 6 * SZ);
  short* wot   = (short*)(ws + 6 * SZ + (size_t)3072 * 1024 * 2);

  prep_and_transpose<<<dim3(12288), 256, 0, stream>>>(x, pos, Wqkv, Wo,
                                                      xb, xpb, wqkvt, wot);
  gemm_qkv<<<dim3(1536), 256, 0, stream>>>(xb, xpb, wqkvt, q, k, vt);
  attn_part<<<dim3(1920), 256, 0, stream>>>(q, k, vt, pO, pL);
  attn_merge<<<dim3(1024), 256, 0, stream>>>(pO, pL, comb);
  gemm_out<<<dim3(512), 256, 0, stream>>>(comb, wot, out);
}